// Round 2
// baseline (834.226 us; speedup 1.0000x reference)
//
#include <hip/hip_runtime.h>
#include <hip/hip_bf16.h>
#include <math.h>

#define ROWS 16
#define NTHR 512
#define TPTS 96
#define CTOT 128
#define NBLK 64

typedef __bf16 bf16x8_t __attribute__((ext_vector_type(8)));
typedef float f32x4_t __attribute__((ext_vector_type(4)));
typedef unsigned short us8_t __attribute__((ext_vector_type(8)));

__device__ __forceinline__ unsigned short f2b(float f) {
    union { float f; unsigned int i; } v; v.f = f;
    unsigned int r = v.i + 0x7fffu + ((v.i >> 16) & 1u);
    return (unsigned short)(r >> 16);
}
__device__ __forceinline__ f32x4_t mfma16(bf16x8_t a, bf16x8_t b, f32x4_t c) {
    return __builtin_amdgcn_mfma_f32_16x16x32_bf16(a, b, c, 0, 0, 0);
}
// LDS/bf16-staged fragment load (8 consecutive bf16 = 16B)
__device__ __forceinline__ bf16x8_t ldfrag(const unsigned short* p) {
    us8_t v = *(const us8_t*)p;
    return __builtin_bit_cast(bf16x8_t, v);
}
// f32 global -> bf16 fragment (RNE), 8 consecutive floats
__device__ __forceinline__ bf16x8_t ldfrag_f32(const float* p) {
    bf16x8_t r;
#pragma unroll
    for (int j = 0; j < 8; ++j) {
        unsigned short us = f2b(p[j]);
        r[j] = __builtin_bit_cast(__bf16, us);
    }
    return r;
}
__device__ __forceinline__ float tanh_fast(float x) {
    float xc = fminf(fmaxf(x, -20.f), 20.f);
    float ez = __expf(-2.f * xc);
    return __fdividef(1.f - ez, 1.f + ez);
}
__device__ __forceinline__ float sigm(float x) {
    return __fdividef(1.f, 1.f + __expf(-x));
}

// Block b owns batch rows [16b, 16b+16). Phases: ODE (95 dopri5 steps, traj -> ws),
// GRU0 (h1 overwrites traj one step delayed), GRU1 (h2 stays in regs), MLP head.
// Per-lane fixed positions: rows quad*4+i (i=0..3), col u = wave*16 + (lane&15).
// All global inputs are FLOAT32; MFMA operands are bf16 (RNE), accum f32.
__global__ void __launch_bounds__(NTHR)
ode_forecaster(const float* __restrict__ yl,
               const float* __restrict__ yh,
               const float* __restrict__ Wode,
               const float* __restrict__ bode,
               const float* __restrict__ Wih0,
               const float* __restrict__ Whh0,
               const float* __restrict__ bih0,
               const float* __restrict__ bhh0,
               const float* __restrict__ Wih1,
               const float* __restrict__ Whh1,
               const float* __restrict__ bih1,
               const float* __restrict__ bhh1,
               const float* __restrict__ W1v,
               const float* __restrict__ b1v,
               const float* __restrict__ W2v,
               const float* __restrict__ b2v,
               float* __restrict__ outp,
               unsigned short* __restrict__ traj)
{
    const int tid  = threadIdx.x;
    const int lane = tid & 63;
    const int wv   = tid >> 6;       // wave 0..7
    const int l15  = lane & 15;
    const int quad = lane >> 4;
    const int r0   = blockIdx.x * ROWS;
    const int row0 = quad * 4;
    const int u    = wv * 16 + l15;  // this lane's feature/output column

    // double-buffered bf16 A-operand staging: [2][16 rows][136 (128 + 8 pad)]
    __shared__ __align__(16) unsigned short hbuf[2][ROWS * 136];
    __shared__ __align__(16) unsigned short hidbuf[ROWS * 72];

    unsigned short* trajB = traj + (size_t)blockIdx.x * (TPTS * ROWS * CTOT);

    // ---------------- init y0 = concat(yl, yh), stage to hbuf[0] + traj[0] ----
    float y[4];
#pragma unroll
    for (int i = 0; i < 4; ++i) {
        int R = r0 + row0 + i;
        y[i] = (u < 32) ? yl[R * 32 + u] : yh[R * 96 + (u - 32)];
        unsigned short yb = f2b(y[i]);
        hbuf[0][(row0 + i) * 136 + u] = yb;
        trajB[(size_t)0 + (row0 + i) * CTOT + u] = yb;
    }

    // ---------------- ODE weights -> registers (B-fragments) ------------------
    bf16x8_t wode[4];
#pragma unroll
    for (int kt = 0; kt < 4; ++kt)
        wode[kt] = ldfrag_f32(Wode + u * 128 + kt * 32 + quad * 8);
    const float bo = bode[u];

    __syncthreads();

    // ---------------- ODE phase: 95 dopri5 steps ------------------------------
    const float dt = 1.0f / 95.0f;
    const float DA1_0 = 0.2f;
    const float DA2_0 = 3.f / 40.f, DA2_1 = 9.f / 40.f;
    const float DA3_0 = 44.f / 45.f, DA3_1 = -56.f / 15.f, DA3_2 = 32.f / 9.f;
    const float DA4_0 = 19372.f / 6561.f, DA4_1 = -25360.f / 2187.f,
                DA4_2 = 64448.f / 6561.f, DA4_3 = -212.f / 729.f;
    const float DA5_0 = 9017.f / 3168.f, DA5_1 = -355.f / 33.f,
                DA5_2 = 46732.f / 5247.f, DA5_3 = 49.f / 176.f, DA5_4 = -5103.f / 18656.f;
    const float B1 = 35.f / 384.f, B3 = 500.f / 1113.f, B4 = 125.f / 192.f,
                B5 = -2187.f / 6784.f, B6 = 11.f / 84.f;

    int p = 0;
    float kr[6][4];
#pragma unroll 1
    for (int t = 0; t < 95; ++t) {
#pragma unroll
        for (int s = 0; s < 6; ++s) {
            // GEMM: k_s = tanh(z @ Wode^T + bo); A from hbuf[p]
            bf16x8_t af[4];
#pragma unroll
            for (int kt = 0; kt < 4; ++kt)
                af[kt] = ldfrag(&hbuf[p][l15 * 136 + kt * 32 + quad * 8]);
            f32x4_t acc = {0.f, 0.f, 0.f, 0.f};
#pragma unroll
            for (int kt = 0; kt < 4; ++kt) acc = mfma16(af[kt], wode[kt], acc);
#pragma unroll
            for (int i = 0; i < 4; ++i) kr[s][i] = tanh_fast(acc[i] + bo);

            if (s < 5) {
#pragma unroll
                for (int i = 0; i < 4; ++i) {
                    float zv = 0.f;
                    if (s == 0) { zv = DA1_0 * kr[0][i]; }
                    else if (s == 1) { zv = DA2_0 * kr[0][i] + DA2_1 * kr[1][i]; }
                    else if (s == 2) { zv = DA3_0 * kr[0][i] + DA3_1 * kr[1][i] + DA3_2 * kr[2][i]; }
                    else if (s == 3) { zv = DA4_0 * kr[0][i] + DA4_1 * kr[1][i] + DA4_2 * kr[2][i] + DA4_3 * kr[3][i]; }
                    else { zv = DA5_0 * kr[0][i] + DA5_1 * kr[1][i] + DA5_2 * kr[2][i] + DA5_3 * kr[3][i] + DA5_4 * kr[4][i]; }
                    hbuf[p ^ 1][(row0 + i) * 136 + u] = f2b(y[i] + dt * zv);
                }
            } else {
#pragma unroll
                for (int i = 0; i < 4; ++i) {
                    float fc = B1 * kr[0][i] + B3 * kr[2][i] + B4 * kr[3][i] + B5 * kr[4][i] + B6 * kr[5][i];
                    y[i] += dt * fc;
                    unsigned short yb = f2b(y[i]);
                    hbuf[p ^ 1][(row0 + i) * 136 + u] = yb;  // z for stage0 of next step
                    trajB[(size_t)(t + 1) * (ROWS * CTOT) + (row0 + i) * CTOT + u] = yb;
                }
            }
            __syncthreads();
            p ^= 1;
        }
    }

    // ---------------- GRU layers (fused per-t, h state in regs) ---------------
    const float* WihL[2] = {Wih0, Wih1};
    const float* WhhL[2] = {Whh0, Whh1};
    const float* bihL[2] = {bih0, bih1};
    const float* bhhL[2] = {bhh0, bhh1};

    float h[4];
#pragma unroll 1
    for (int layer = 0; layer < 2; ++layer) {
        const float* Wih = WihL[layer];
        const float* Whh = WhhL[layer];
        // B-fragments for this wave's 3 gate tiles {wv, 8+wv, 16+wv} -> gate cols 128g+u
        bf16x8_t wih[3][4], whh[3][4];
#pragma unroll
        for (int g = 0; g < 3; ++g) {
            int nrow = g * 128 + u;   // row of W_ih/W_hh (384 rows)
#pragma unroll
            for (int kt = 0; kt < 4; ++kt) {
                wih[g][kt] = ldfrag_f32(Wih + nrow * 128 + kt * 32 + quad * 8);
                whh[g][kt] = ldfrag_f32(Whh + nrow * 128 + kt * 32 + quad * 8);
            }
        }
        const float bir  = bihL[layer][u];
        const float biz  = bihL[layer][128 + u];
        const float bin_ = bihL[layer][256 + u];
        const float bhr  = bhhL[layer][u];
        const float bhz  = bhhL[layer][128 + u];
        const float bhn  = bhhL[layer][256 + u];

#pragma unroll
        for (int i = 0; i < 4; ++i) h[i] = 0.f;
        p = 0;
        for (int idx = tid; idx < ROWS * 136; idx += NTHR) hbuf[0][idx] = 0;
        __syncthreads();

#pragma unroll 1
        for (int t = 0; t < TPTS; ++t) {
            // delayed write of h1_{t-1} over traj[t-1] (consumed last iter)
            if (layer == 0 && t > 0) {
#pragma unroll
                for (int i = 0; i < 4; ++i)
                    trajB[(size_t)(t - 1) * (ROWS * CTOT) + (row0 + i) * CTOT + u] = f2b(h[i]);
            }
            const unsigned short* xp = trajB + (size_t)t * (ROWS * CTOT) + l15 * CTOT;
            bf16x8_t ax[4], ah[4];
#pragma unroll
            for (int kt = 0; kt < 4; ++kt) ax[kt] = ldfrag(xp + kt * 32 + quad * 8);
#pragma unroll
            for (int kt = 0; kt < 4; ++kt)
                ah[kt] = ldfrag(&hbuf[p][l15 * 136 + kt * 32 + quad * 8]);

            f32x4_t gi0 = {0.f,0.f,0.f,0.f}, gi1 = {0.f,0.f,0.f,0.f}, gi2 = {0.f,0.f,0.f,0.f};
            f32x4_t gh0 = {0.f,0.f,0.f,0.f}, gh1 = {0.f,0.f,0.f,0.f}, gh2 = {0.f,0.f,0.f,0.f};
#pragma unroll
            for (int kt = 0; kt < 4; ++kt) {
                gi0 = mfma16(ax[kt], wih[0][kt], gi0);
                gi1 = mfma16(ax[kt], wih[1][kt], gi1);
                gi2 = mfma16(ax[kt], wih[2][kt], gi2);
                gh0 = mfma16(ah[kt], whh[0][kt], gh0);
                gh1 = mfma16(ah[kt], whh[1][kt], gh1);
                gh2 = mfma16(ah[kt], whh[2][kt], gh2);
            }
#pragma unroll
            for (int i = 0; i < 4; ++i) {
                float rr = sigm((gi0[i] + bir) + (gh0[i] + bhr));
                float zz = sigm((gi1[i] + biz) + (gh1[i] + bhz));
                float nn = tanh_fast((gi2[i] + bin_) + rr * (gh2[i] + bhn));
                h[i] = (1.f - zz) * nn + zz * h[i];
                hbuf[p ^ 1][(row0 + i) * 136 + u] = f2b(h[i]);
            }
            __syncthreads();
            p ^= 1;
        }
        if (layer == 0) {
#pragma unroll
            for (int i = 0; i < 4; ++i)
                trajB[(size_t)95 * (ROWS * CTOT) + (row0 + i) * CTOT + u] = f2b(h[i]);
        }
        // hbuf[p] now holds staged bf16 of this layer's final h (for layer1: h2)
    }

    // ---------------- MLP head ------------------------------------------------
    // hidden = gelu(h2 @ W1^T + b1)  [16 x 64], waves 0..3
    if (wv < 4) {
        bf16x8_t a4[4], bw[4];
#pragma unroll
        for (int kt = 0; kt < 4; ++kt) {
            a4[kt] = ldfrag(&hbuf[p][l15 * 136 + kt * 32 + quad * 8]);
            bw[kt] = ldfrag_f32(W1v + (wv * 16 + l15) * 128 + kt * 32 + quad * 8);
        }
        f32x4_t acc = {0.f, 0.f, 0.f, 0.f};
#pragma unroll
        for (int kt = 0; kt < 4; ++kt) acc = mfma16(a4[kt], bw[kt], acc);
        const float bb = b1v[wv * 16 + l15];
#pragma unroll
        for (int i = 0; i < 4; ++i) {
            float x = acc[i] + bb;
            float g = 0.5f * x * (1.0f + erff(x * 0.70710678118654752f));
            hidbuf[(row0 + i) * 72 + wv * 16 + l15] = f2b(g);
        }
    }
    __syncthreads();

    // pred = hidden @ W2^T + b2  [16 x 3072], 24 N-tiles per wave, K=64
    bf16x8_t ahid[2];
#pragma unroll
    for (int kt = 0; kt < 2; ++kt)
        ahid[kt] = ldfrag(&hidbuf[l15 * 72 + kt * 32 + quad * 8]);
#pragma unroll 1
    for (int j = 0; j < 24; ++j) {
        int n = (wv * 24 + j) * 16 + l15;   // output column 0..3071 = W2 row
        bf16x8_t bb0 = ldfrag_f32(W2v + n * 64 + quad * 8);
        bf16x8_t bb1 = ldfrag_f32(W2v + n * 64 + 32 + quad * 8);
        f32x4_t acc = {0.f, 0.f, 0.f, 0.f};
        acc = mfma16(ahid[0], bb0, acc);
        acc = mfma16(ahid[1], bb1, acc);
        const float bv = b2v[n];
#pragma unroll
        for (int i = 0; i < 4; ++i)
            outp[(size_t)(r0 + row0 + i) * 3072 + n] = acc[i] + bv;
    }
}

extern "C" void kernel_launch(void* const* d_in, const int* in_sizes, int n_in,
                              void* d_out, int out_size, void* d_ws, size_t ws_size,
                              hipStream_t stream) {
    // setup_inputs order: 0:x(unused) 1:yl 2:yh 3:W_ode 4:b_ode 5:W_ih0 6:W_hh0
    // 7:b_ih0 8:b_hh0 9:W_ih1 10:W_hh1 11:b_ih1 12:b_hh1 13:W1 14:b1 15:W2 16:b2
    const float* yl   = (const float*)d_in[1];
    const float* yh   = (const float*)d_in[2];
    const float* Wode = (const float*)d_in[3];
    const float* bode = (const float*)d_in[4];
    const float* Wih0 = (const float*)d_in[5];
    const float* Whh0 = (const float*)d_in[6];
    const float* bih0 = (const float*)d_in[7];
    const float* bhh0 = (const float*)d_in[8];
    const float* Wih1 = (const float*)d_in[9];
    const float* Whh1 = (const float*)d_in[10];
    const float* bih1 = (const float*)d_in[11];
    const float* bhh1 = (const float*)d_in[12];
    const float* W1v  = (const float*)d_in[13];
    const float* b1v  = (const float*)d_in[14];
    const float* W2v  = (const float*)d_in[15];
    const float* b2v  = (const float*)d_in[16];

    ode_forecaster<<<dim3(NBLK), dim3(NTHR), 0, stream>>>(
        yl, yh, Wode, bode, Wih0, Whh0, bih0, bhh0,
        Wih1, Whh1, bih1, bhh1, W1v, b1v, W2v, b2v,
        (float*)d_out, (unsigned short*)d_ws);
}